// Round 12
// baseline (282.284 us; speedup 1.0000x reference)
//
#include <hip/hip_runtime.h>

#define NN 50000
#define NE 800000

typedef __attribute__((ext_vector_type(8))) short bf16x8;
typedef __attribute__((ext_vector_type(4))) float f32x4;

// swizzled slot within a 1KB subtile (64 x 16B slots); bijective involution,
// applied on both write and read so correctness is layout-independent.
#define SWS(s, kt) ((s) ^ (((s) >> 3) & 6) ^ ((kt) & 3))

// packed f32->bf16 (RNE) via native instruction
__device__ __forceinline__ unsigned cvtpk(float lo, float hi) {
    unsigned r;
    asm("v_cvt_pk_bf16_f32 %0, %1, %2" : "=v"(r) : "v"(lo), "v"(hi));
    return r;
}
__device__ __forceinline__ uint2 pack4(float a, float b, float c, float d) {
    return make_uint2(cvtpk(a, b), cvtpk(c, d));
}

// ---------------------------------------------------------------------------
// Fused prep: weights->bf16 fragments | x->bf16 | dst histogram (+rank).
// ---------------------------------------------------------------------------
__device__ __forceinline__ void prep_weights_body(int tid,
        const float* __restrict__ W1, const float* __restrict__ W2,
        const float* __restrict__ U1, const float* __restrict__ U2,
        unsigned short* __restrict__ ws) {
    const float* src; unsigned short* dst; int K;
    if (tid < 6144)        { src = W1; dst = ws;         K = 192; }
    else if (tid < 10240)  { tid -= 6144;  src = W2; dst = ws + 24576; K = 128; }
    else if (tid < 18432)  { tid -= 10240; src = U1; dst = ws + 40960; K = 256; }
    else if (tid < 22528)  { tid -= 18432; src = U2; dst = ws + 73728; K = 128; }
    else return;
    const int m = tid & 127, k = (tid >> 7) * 4;
    const int KT = K >> 5;
    uint2 p = pack4(src[(k + 0) * 128 + m], src[(k + 1) * 128 + m],
                    src[(k + 2) * 128 + m], src[(k + 3) * 128 + m]);
    const int mt = m >> 4, kt = k >> 5, lane = (m & 15) + (((k & 31) >> 3) << 4);
    const int off = (((mt * KT + kt) << 9) + (lane << 3) + ((k & 4) ? 4 : 0));
    *reinterpret_cast<uint2*>(dst + off) = p;
}

__global__ __launch_bounds__(256)
void prep_all(const float* __restrict__ W1, const float* __restrict__ W2,
              const float* __restrict__ U1, const float* __restrict__ U2,
              const float* __restrict__ x, const int* __restrict__ ei,
              unsigned short* __restrict__ ws, unsigned short* __restrict__ xb,
              int* __restrict__ counts, int* __restrict__ rank) {
    const int b = blockIdx.x;
    if (b < 88) {
        prep_weights_body(b * 256 + threadIdx.x, W1, W2, U1, U2, ws);
    } else if (b < 3213) {
        const int i = ((b - 88) * 256 + threadIdx.x) * 8;
        if (i >= NN * 128) return;
        const float4 a = *reinterpret_cast<const float4*>(&x[i]);
        const float4 c = *reinterpret_cast<const float4*>(&x[i + 4]);
        *reinterpret_cast<uint4*>(&xb[i]) =
            make_uint4(cvtpk(a.x, a.y), cvtpk(a.z, a.w), cvtpk(c.x, c.y), cvtpk(c.z, c.w));
    } else {
        const int e = (b - 3213) * 256 + threadIdx.x;
        if (e < NE) rank[e] = atomicAdd(&counts[ei[NE + e]], 1);
    }
}

__global__ void prep_weights(const float* __restrict__ W1, const float* __restrict__ W2,
                             const float* __restrict__ U1, const float* __restrict__ U2,
                             unsigned short* __restrict__ ws) {
    prep_weights_body(blockIdx.x * blockDim.x + threadIdx.x, W1, W2, U1, U2, ws);
}

__global__ void hist_kernel(const int* __restrict__ ei, int* __restrict__ counts,
                            int* __restrict__ rank) {
    const int e = blockIdx.x * blockDim.x + threadIdx.x;
    if (e < NE) rank[e] = atomicAdd(&counts[ei[NE + e]], 1);
}

// ---------------------------------------------------------------------------
// CSR scan: scan1 (per-256-block exclusive) + scan2 (block offsets).
// Final offset of node i = offs[i] + boffs[i>>8]; consumers add it inline.
// ---------------------------------------------------------------------------
__global__ __launch_bounds__(256)
void scan1_kernel(const int* __restrict__ counts, int* __restrict__ offs,
                  int* __restrict__ bsums) {
    __shared__ int wsum[4];
    const int t = threadIdx.x, lane = t & 63, w = t >> 6;
    const int i = blockIdx.x * 256 + t;
    const int v = (i < NN) ? counts[i] : 0;
    int s = v;
#pragma unroll
    for (int d = 1; d < 64; d <<= 1) {
        int u = __shfl_up(s, d, 64);
        if (lane >= d) s += u;
    }
    if (lane == 63) wsum[w] = s;
    __syncthreads();
    if (t == 0) {
        int a = 0;
#pragma unroll
        for (int k = 0; k < 4; ++k) { int tmp = wsum[k]; wsum[k] = a; a += tmp; }
    }
    __syncthreads();
    const int excl = wsum[w] + s - v;
    if (i < NN) offs[i] = excl;
    if (t == 255) bsums[blockIdx.x] = wsum[3] + s;
}

__global__ __launch_bounds__(256)
void scan2_kernel(const int* __restrict__ bsums, int* __restrict__ boffs) {
    __shared__ int wsum[4];
    const int t = threadIdx.x, lane = t & 63, w = t >> 6;
    const int v = (t < 196) ? bsums[t] : 0;
    int s = v;
#pragma unroll
    for (int d = 1; d < 64; d <<= 1) {
        int u = __shfl_up(s, d, 64);
        if (lane >= d) s += u;
    }
    if (lane == 63) wsum[w] = s;
    __syncthreads();
    if (t == 0) {
        int a = 0;
#pragma unroll
        for (int k = 0; k < 4; ++k) { int tmp = wsum[k]; wsum[k] = a; a += tmp; }
    }
    __syncthreads();
    boffs[t] = wsum[w] + s - v;
}

// ---------------------------------------------------------------------------
// Edge kernel (r11 shape, 2 barriers/tile): 512 thr = 8 waves, 1 mtile/wave.
// CSR position computed inline: offs[dst] + boffs[dst>>8] + rank[e].
// ---------------------------------------------------------------------------
template <int XBF>
__global__ __launch_bounds__(512)
void edge_kernel2(const float* __restrict__ x,
                  const unsigned short* __restrict__ xb,
                  const float* __restrict__ pe,
                  const float* __restrict__ b1,
                  const float* __restrict__ b2,
                  const int* __restrict__ ei,
                  const int* __restrict__ rank,
                  const int* __restrict__ offs,
                  const int* __restrict__ boffs,
                  const unsigned short* __restrict__ wf,
                  unsigned short* __restrict__ msg)
{
    __shared__ __align__(16) unsigned char Asw[24576];  // 6 kt x 4 nt x 1KB
    __shared__ __align__(16) unsigned char Hsw[16384];  // 4 kt x 4 nt x 1KB

    const int t = threadIdx.x;
    const int l = t & 63;
    const int w = t >> 6;       // wave = mtile
    const int g = l >> 4;

    bf16x8 w1r[6], w2r[4];
    {
        const bf16x8* wp1 = reinterpret_cast<const bf16x8*>(wf);
        const bf16x8* wp2 = reinterpret_cast<const bf16x8*>(wf + 24576);
#pragma unroll
        for (int kt = 0; kt < 6; ++kt) w1r[kt] = wp1[(w * 6 + kt) * 64 + l];
#pragma unroll
        for (int kt = 0; kt < 4; ++kt) w2r[kt] = wp2[(w * 4 + kt) * 64 + l];
    }
    const float4 b1v = *reinterpret_cast<const float4*>(&b1[16 * w + 4 * g]);
    const float4 b2v = *reinterpret_cast<const float4*>(&b2[16 * w + 4 * g]);

    const int le = t >> 3;              // staged edge 0..63
    const int sub = t & 7;              // k-subgroup
    const int nt_s = le >> 4;
    const int lane_s = (le & 15) + ((sub & 3) << 4);

    uint4  rxb[2];
    float4 rxf[4];
    float4 rpf[2];

    const int tile0 = blockIdx.x * 5;

    // prefetch tile 0
    {
        const int e0 = tile0 * 64;
        const int src = ei[e0 + le];
        if constexpr (XBF) {
#pragma unroll
            for (int j = 0; j < 2; ++j)
                rxb[j] = *reinterpret_cast<const uint4*>(&xb[(size_t)src * 128 + sub * 8 + 64 * j]);
        } else {
#pragma unroll
            for (int j = 0; j < 2; ++j) {
                rxf[2 * j]     = *reinterpret_cast<const float4*>(&x[(size_t)src * 128 + sub * 8 + 64 * j]);
                rxf[2 * j + 1] = *reinterpret_cast<const float4*>(&x[(size_t)src * 128 + sub * 8 + 64 * j + 4]);
            }
        }
        rpf[0] = *reinterpret_cast<const float4*>(&pe[(size_t)(e0 + le) * 64 + sub * 8]);
        rpf[1] = *reinterpret_cast<const float4*>(&pe[(size_t)(e0 + le) * 64 + sub * 8 + 4]);
    }

    for (int ti = 0; ti < 5; ++ti) {
        const int e0 = (tile0 + ti) * 64;
        int cp[4];
#pragma unroll
        for (int nt = 0; nt < 4; ++nt) {
            const int e = e0 + nt * 16 + (l & 15);
            const int dst = ei[NE + e];
            cp[nt] = offs[dst] + boffs[dst >> 8] + rank[e];
        }

        // (sync-A removed: ordered by previous iteration's sync-C)

        // ---- stage regs -> Asw (swizzled B-fragment layout) ----
        {
#pragma unroll
            for (int j = 0; j < 2; ++j) {
                const int kt = (sub >> 2) + 2 * j;
                uint4 v;
                if constexpr (XBF) v = rxb[j];
                else v = make_uint4(cvtpk(rxf[2 * j].x, rxf[2 * j].y), cvtpk(rxf[2 * j].z, rxf[2 * j].w),
                                    cvtpk(rxf[2 * j + 1].x, rxf[2 * j + 1].y), cvtpk(rxf[2 * j + 1].z, rxf[2 * j + 1].w));
                *reinterpret_cast<uint4*>(Asw + ((kt * 4 + nt_s) << 10) + (SWS(lane_s, kt) << 4)) = v;
            }
            const int ktp = 4 + (sub >> 2);
            *reinterpret_cast<uint4*>(Asw + ((ktp * 4 + nt_s) << 10) + (SWS(lane_s, ktp) << 4)) =
                make_uint4(cvtpk(rpf[0].x, rpf[0].y), cvtpk(rpf[0].z, rpf[0].w),
                           cvtpk(rpf[1].x, rpf[1].y), cvtpk(rpf[1].z, rpf[1].w));
        }

        // prefetch next tile (loads overlap this tile's MFMAs)
        if (ti < 4) {
            const int e0n = e0 + 64;
            const int srcn = ei[e0n + le];
            if constexpr (XBF) {
#pragma unroll
                for (int j = 0; j < 2; ++j)
                    rxb[j] = *reinterpret_cast<const uint4*>(&xb[(size_t)srcn * 128 + sub * 8 + 64 * j]);
            } else {
#pragma unroll
                for (int j = 0; j < 2; ++j) {
                    rxf[2 * j]     = *reinterpret_cast<const float4*>(&x[(size_t)srcn * 128 + sub * 8 + 64 * j]);
                    rxf[2 * j + 1] = *reinterpret_cast<const float4*>(&x[(size_t)srcn * 128 + sub * 8 + 64 * j + 4]);
                }
            }
            rpf[0] = *reinterpret_cast<const float4*>(&pe[(size_t)(e0n + le) * 64 + sub * 8]);
            rpf[1] = *reinterpret_cast<const float4*>(&pe[(size_t)(e0n + le) * 64 + sub * 8 + 4]);
        }

        __syncthreads();   // [B] Asw staged

        // ---- layer 1: K=192 ----
        f32x4 acc[4];
#pragma unroll
        for (int nt = 0; nt < 4; ++nt) acc[nt] = (f32x4){0.f, 0.f, 0.f, 0.f};
#pragma unroll
        for (int kt = 0; kt < 6; ++kt) {
#pragma unroll
            for (int nt = 0; nt < 4; ++nt) {
                const bf16x8 af = *reinterpret_cast<const bf16x8*>(
                    Asw + ((kt * 4 + nt) << 10) + (SWS(l, kt) << 4));
                acc[nt] = __builtin_amdgcn_mfma_f32_16x16x32_bf16(w1r[kt], af, acc[nt], 0, 0, 0);
            }
        }

        // ---- bias + relu -> Hsw ----
        {
            const int kt2 = (16 * w + 4 * g) >> 5;
            const int lane2 = (l & 15) + ((2 * (w & 1) + (g >> 1)) << 4);
            const int bo = (g & 1) << 3;
#pragma unroll
            for (int nt = 0; nt < 4; ++nt) {
                float v0 = fmaxf(acc[nt][0] + b1v.x, 0.f);
                float v1 = fmaxf(acc[nt][1] + b1v.y, 0.f);
                float v2 = fmaxf(acc[nt][2] + b1v.z, 0.f);
                float v3 = fmaxf(acc[nt][3] + b1v.w, 0.f);
                *reinterpret_cast<uint2*>(Hsw + ((kt2 * 4 + nt) << 10) + (SWS(lane2, kt2) << 4) + bo) =
                    make_uint2(cvtpk(v0, v1), cvtpk(v2, v3));
            }
        }

        __syncthreads();   // [C] Hsw ready; all Asw L1 reads complete

        // ---- layer 2: K=128 ----
#pragma unroll
        for (int nt = 0; nt < 4; ++nt) acc[nt] = (f32x4){0.f, 0.f, 0.f, 0.f};
#pragma unroll
        for (int kt = 0; kt < 4; ++kt) {
#pragma unroll
            for (int nt = 0; nt < 4; ++nt) {
                const bf16x8 hf = *reinterpret_cast<const bf16x8*>(
                    Hsw + ((kt * 4 + nt) << 10) + (SWS(l, kt) << 4));
                acc[nt] = __builtin_amdgcn_mfma_f32_16x16x32_bf16(w2r[kt], hf, acc[nt], 0, 0, 0);
            }
        }

        // ---- bias + CSR-ordered msg store ----
        const int mbase = 16 * w + 4 * g;
#pragma unroll
        for (int nt = 0; nt < 4; ++nt) {
            *reinterpret_cast<uint2*>(&msg[(size_t)cp[nt] * 128 + mbase]) =
                make_uint2(cvtpk(acc[nt][0] + b2v.x, acc[nt][1] + b2v.y),
                           cvtpk(acc[nt][2] + b2v.z, acc[nt][3] + b2v.w));
        }
    }
}

// ---------------------------------------------------------------------------
// Fused node kernel (r9-proven; start = offs[node] + boffs[node>>8])
// ---------------------------------------------------------------------------
template <int XBF>
__global__ __launch_bounds__(512)
void node_fused(const float* __restrict__ x,
                const unsigned short* __restrict__ xb,
                const float* __restrict__ c1,
                const float* __restrict__ c2,
                const unsigned short* __restrict__ wf,
                const int* __restrict__ offs,
                const int* __restrict__ boffs,
                const int* __restrict__ counts,
                const unsigned short* __restrict__ msg,
                float* __restrict__ out)
{
    __shared__ __align__(16) unsigned char Asw[32768];
    __shared__ __align__(16) unsigned char Hsw[16384];

    const int t = threadIdx.x;
    const int l = t & 63;
    const int w = t >> 6;
    const int g = l >> 4;

    bf16x8 u1r[8], u2r[4];
    {
        const bf16x8* up1 = reinterpret_cast<const bf16x8*>(wf + 40960);
        const bf16x8* up2 = reinterpret_cast<const bf16x8*>(wf + 73728);
#pragma unroll
        for (int kt = 0; kt < 8; ++kt) u1r[kt] = up1[(w * 8 + kt) * 64 + l];
#pragma unroll
        for (int kt = 0; kt < 4; ++kt) u2r[kt] = up2[(w * 4 + kt) * 64 + l];
    }
    const float4 c1v = *reinterpret_cast<const float4*>(&c1[16 * w + 4 * g]);
    const float4 c2v = *reinterpret_cast<const float4*>(&c2[16 * w + 4 * g]);

    const int n0 = blockIdx.x * 64;
    const int le = t >> 3;
    const int q  = t & 7;
    const int nt_s = le >> 4;
    const int node = n0 + le;
    const bool valid = node < NN;

    float a16[16];
#pragma unroll
    for (int i = 0; i < 16; ++i) a16[i] = 0.f;
    int start = 0, cnt = 0;
    if (valid) { start = offs[node] + boffs[node >> 8]; cnt = counts[node]; }
    for (int j = 0; j < cnt; ++j) {
        const uint4* mp = reinterpret_cast<const uint4*>(&msg[(size_t)(start + j) * 128 + q * 16]);
        const uint4 u0 = mp[0], u1 = mp[1];
        const unsigned arr[8] = {u0.x, u0.y, u0.z, u0.w, u1.x, u1.y, u1.z, u1.w};
#pragma unroll
        for (int r = 0; r < 8; ++r) {
            union { unsigned u; float f; } lo, hi;
            lo.u = arr[r] << 16;
            hi.u = arr[r] & 0xFFFF0000u;
            a16[2 * r]     += lo.f;
            a16[2 * r + 1] += hi.f;
        }
    }

#pragma unroll
    for (int i = 0; i < 2; ++i) {
        const int o = 2 * q + i;
        const int kt = o >> 2;
        const int slot = (le & 15) + ((o & 3) << 4);
        uint4 v = make_uint4(0u, 0u, 0u, 0u);
        if (valid) {
            if constexpr (XBF) {
                v = *reinterpret_cast<const uint4*>(&xb[(size_t)node * 128 + o * 8]);
            } else {
                const float4 f0 = *reinterpret_cast<const float4*>(&x[(size_t)node * 128 + o * 8]);
                const float4 f1 = *reinterpret_cast<const float4*>(&x[(size_t)node * 128 + o * 8 + 4]);
                v = make_uint4(cvtpk(f0.x, f0.y), cvtpk(f0.z, f0.w),
                               cvtpk(f1.x, f1.y), cvtpk(f1.z, f1.w));
            }
        }
        *reinterpret_cast<uint4*>(Asw + ((kt * 4 + nt_s) << 10) + (SWS(slot, kt) << 4)) = v;
    }

    {
        const int kt = 4 + (q >> 1);
#pragma unroll
        for (int i = 0; i < 2; ++i) {
            const int j4 = 2 * (q & 1) + i;
            const int slot = (le & 15) + (j4 << 4);
            *reinterpret_cast<uint4*>(Asw + ((kt * 4 + nt_s) << 10) + (SWS(slot, kt) << 4)) =
                make_uint4(cvtpk(a16[8 * i + 0], a16[8 * i + 1]), cvtpk(a16[8 * i + 2], a16[8 * i + 3]),
                           cvtpk(a16[8 * i + 4], a16[8 * i + 5]), cvtpk(a16[8 * i + 6], a16[8 * i + 7]));
        }
    }
    __syncthreads();

    f32x4 acc[4];
#pragma unroll
    for (int nt = 0; nt < 4; ++nt) acc[nt] = (f32x4){0.f, 0.f, 0.f, 0.f};
#pragma unroll
    for (int kt = 0; kt < 8; ++kt) {
#pragma unroll
        for (int nt = 0; nt < 4; ++nt) {
            const bf16x8 af = *reinterpret_cast<const bf16x8*>(
                Asw + ((kt * 4 + nt) << 10) + (SWS(l, kt) << 4));
            acc[nt] = __builtin_amdgcn_mfma_f32_16x16x32_bf16(u1r[kt], af, acc[nt], 0, 0, 0);
        }
    }

    {
        const int kt2 = (16 * w + 4 * g) >> 5;
        const int lane2 = (l & 15) + ((2 * (w & 1) + (g >> 1)) << 4);
        const int bo = (g & 1) << 3;
#pragma unroll
        for (int nt = 0; nt < 4; ++nt) {
            float v0 = fmaxf(acc[nt][0] + c1v.x, 0.f);
            float v1 = fmaxf(acc[nt][1] + c1v.y, 0.f);
            float v2 = fmaxf(acc[nt][2] + c1v.z, 0.f);
            float v3 = fmaxf(acc[nt][3] + c1v.w, 0.f);
            *reinterpret_cast<uint2*>(Hsw + ((kt2 * 4 + nt) << 10) + (SWS(lane2, kt2) << 4) + bo) =
                make_uint2(cvtpk(v0, v1), cvtpk(v2, v3));
        }
    }
    __syncthreads();

    f32x4 a2[4];
#pragma unroll
    for (int nt = 0; nt < 4; ++nt) a2[nt] = (f32x4){0.f, 0.f, 0.f, 0.f};
#pragma unroll
    for (int kt = 0; kt < 4; ++kt) {
#pragma unroll
        for (int nt = 0; nt < 4; ++nt) {
            const bf16x8 hf = *reinterpret_cast<const bf16x8*>(
                Hsw + ((kt * 4 + nt) << 10) + (SWS(l, kt) << 4));
            a2[nt] = __builtin_amdgcn_mfma_f32_16x16x32_bf16(u2r[kt], hf, a2[nt], 0, 0, 0);
        }
    }

    const int mbase = 16 * w + 4 * g;
#pragma unroll
    for (int nt = 0; nt < 4; ++nt) {
        const int n = n0 + nt * 16 + (l & 15);
        if (n < NN) {
            float4 o;
            o.x = a2[nt][0] + c2v.x;
            o.y = a2[nt][1] + c2v.y;
            o.z = a2[nt][2] + c2v.z;
            o.w = a2[nt][3] + c2v.w;
            *reinterpret_cast<float4*>(&out[(size_t)n * 128 + mbase]) = o;
        }
    }
}

// ---------------------------------------------------------------------------
// Legacy fallback (small workspace): atomic scatter edge + in-place node.
// ---------------------------------------------------------------------------
__global__ __launch_bounds__(256)
void edge_atomic(const float* __restrict__ x, const float* __restrict__ pe,
                 const float* __restrict__ b1, const float* __restrict__ b2,
                 const int* __restrict__ ei, const unsigned short* __restrict__ wf,
                 float* __restrict__ agg)
{
    __shared__ __align__(16) unsigned char smem[24576 + 16384];
    unsigned char* Asw = smem;
    unsigned char* Hsw = smem + 24576;

    const int t = threadIdx.x;
    const int l = t & 63;
    const int w = t >> 6;
    const int g = l >> 4;

    bf16x8 w1r[2][6], w2r[2][4];
    {
        const bf16x8* wp1 = reinterpret_cast<const bf16x8*>(wf);
        const bf16x8* wp2 = reinterpret_cast<const bf16x8*>(wf + 24576);
#pragma unroll
        for (int dm = 0; dm < 2; ++dm) {
            const int mt = 2 * w + dm;
#pragma unroll
            for (int kt = 0; kt < 6; ++kt) w1r[dm][kt] = wp1[(mt * 6 + kt) * 64 + l];
#pragma unroll
            for (int kt = 0; kt < 4; ++kt) w2r[dm][kt] = wp2[(mt * 4 + kt) * 64 + l];
        }
    }
    float4 b1v[2], b2v[2];
#pragma unroll
    for (int dm = 0; dm < 2; ++dm) {
        b1v[dm] = *reinterpret_cast<const float4*>(&b1[32 * w + 16 * dm + 4 * g]);
        b2v[dm] = *reinterpret_cast<const float4*>(&b2[32 * w + 16 * dm + 4 * g]);
    }

    const int le = t >> 2;
    const int lq = (t & 3) * 4;
    const int nt_s = le >> 4;

    for (int tile = blockIdx.x * 5; tile < blockIdx.x * 5 + 5; ++tile) {
        const int e0 = tile * 64;
        const int src = ei[e0 + le];
#pragma unroll
        for (int j = 0; j < 12; ++j) {
            const int k = lq + 16 * j;
            float4 av;
            if (j < 8) av = *reinterpret_cast<const float4*>(&x[(size_t)src * 128 + k]);
            else       av = *reinterpret_cast<const float4*>(&pe[(size_t)(e0 + le) * 64 + (k - 128)]);
            const int kt = k >> 5;
            const int lane = (le & 15) + (((k & 31) >> 3) << 4);
            const int off = ((kt * 4 + nt_s) << 10) + (lane << 4) + ((k & 4) << 1);
            *reinterpret_cast<uint2*>(Asw + off) = pack4(av.x, av.y, av.z, av.w);
        }
        int dstv[4];
#pragma unroll
        for (int nt = 0; nt < 4; ++nt) dstv[nt] = ei[NE + e0 + nt * 16 + (l & 15)];
        __syncthreads();

        f32x4 acc[2][4];
#pragma unroll
        for (int dm = 0; dm < 2; ++dm)
#pragma unroll
            for (int nt = 0; nt < 4; ++nt) acc[dm][nt] = (f32x4){0.f, 0.f, 0.f, 0.f};
#pragma unroll
        for (int kt = 0; kt < 6; ++kt) {
#pragma unroll
            for (int nt = 0; nt < 4; ++nt) {
                const bf16x8 af = *reinterpret_cast<const bf16x8*>(Asw + ((kt * 4 + nt) << 10) + (l << 4));
                acc[0][nt] = __builtin_amdgcn_mfma_f32_16x16x32_bf16(w1r[0][kt], af, acc[0][nt], 0, 0, 0);
                acc[1][nt] = __builtin_amdgcn_mfma_f32_16x16x32_bf16(w1r[1][kt], af, acc[1][nt], 0, 0, 0);
            }
        }
#pragma unroll
        for (int dm = 0; dm < 2; ++dm) {
            const float bb[4] = {b1v[dm].x, b1v[dm].y, b1v[dm].z, b1v[dm].w};
            const int lane2 = (l & 15) + ((2 * dm + (g >> 1)) << 4);
#pragma unroll
            for (int nt = 0; nt < 4; ++nt) {
                float v0 = fmaxf(acc[dm][nt][0] + bb[0], 0.f);
                float v1 = fmaxf(acc[dm][nt][1] + bb[1], 0.f);
                float v2 = fmaxf(acc[dm][nt][2] + bb[2], 0.f);
                float v3 = fmaxf(acc[dm][nt][3] + bb[3], 0.f);
                const int off = ((w * 4 + nt) << 10) + (lane2 << 4) + ((g & 1) << 3);
                *reinterpret_cast<uint2*>(Hsw + off) = pack4(v0, v1, v2, v3);
            }
        }
        __syncthreads();

        f32x4 acc2[2][4];
#pragma unroll
        for (int dm = 0; dm < 2; ++dm)
#pragma unroll
            for (int nt = 0; nt < 4; ++nt) acc2[dm][nt] = (f32x4){0.f, 0.f, 0.f, 0.f};
#pragma unroll
        for (int kt = 0; kt < 4; ++kt) {
#pragma unroll
            for (int nt = 0; nt < 4; ++nt) {
                const bf16x8 hf = *reinterpret_cast<const bf16x8*>(Hsw + ((kt * 4 + nt) << 10) + (l << 4));
                acc2[0][nt] = __builtin_amdgcn_mfma_f32_16x16x32_bf16(w2r[0][kt], hf, acc2[0][nt], 0, 0, 0);
                acc2[1][nt] = __builtin_amdgcn_mfma_f32_16x16x32_bf16(w2r[1][kt], hf, acc2[1][nt], 0, 0, 0);
            }
        }
#pragma unroll
        for (int dm = 0; dm < 2; ++dm) {
            const float bb[4] = {b2v[dm].x, b2v[dm].y, b2v[dm].z, b2v[dm].w};
            const int mbase = 32 * w + 16 * dm + 4 * g;
#pragma unroll
            for (int nt = 0; nt < 4; ++nt) {
                float* ap = &agg[(size_t)dstv[nt] * 128 + mbase];
                atomicAdd(ap + 0, acc2[dm][nt][0] + bb[0]);
                atomicAdd(ap + 1, acc2[dm][nt][1] + bb[1]);
                atomicAdd(ap + 2, acc2[dm][nt][2] + bb[2]);
                atomicAdd(ap + 3, acc2[dm][nt][3] + bb[3]);
            }
        }
    }
}

__global__ __launch_bounds__(256)
void node_legacy(const float* __restrict__ x,
                 const float* __restrict__ c1,
                 const float* __restrict__ c2,
                 const unsigned short* __restrict__ wf,
                 float* __restrict__ out)
{
    __shared__ __align__(16) unsigned char smem[32768 + 16384];
    unsigned char* Asw = smem;
    unsigned char* Hsw = smem + 32768;

    const int t = threadIdx.x;
    const int l = t & 63;
    const int w = t >> 6;
    const int g = l >> 4;

    bf16x8 u1r[2][8], u2r[2][4];
    {
        const bf16x8* up1 = reinterpret_cast<const bf16x8*>(wf + 40960);
        const bf16x8* up2 = reinterpret_cast<const bf16x8*>(wf + 73728);
#pragma unroll
        for (int dm = 0; dm < 2; ++dm) {
            const int mt = 2 * w + dm;
#pragma unroll
            for (int kt = 0; kt < 8; ++kt) u1r[dm][kt] = up1[(mt * 8 + kt) * 64 + l];
#pragma unroll
            for (int kt = 0; kt < 4; ++kt) u2r[dm][kt] = up2[(mt * 4 + kt) * 64 + l];
        }
    }
    float4 c1v[2], c2v[2];
#pragma unroll
    for (int dm = 0; dm < 2; ++dm) {
        c1v[dm] = *reinterpret_cast<const float4*>(&c1[32 * w + 16 * dm + 4 * g]);
        c2v[dm] = *reinterpret_cast<const float4*>(&c2[32 * w + 16 * dm + 4 * g]);
    }

    const int n0 = blockIdx.x * 64;
    const int le = t >> 2;
    const int lq = (t & 3) * 4;
    const int nt_s = le >> 4;
    const int node = n0 + le;
    const bool valid = node < NN;

#pragma unroll
    for (int j = 0; j < 16; ++j) {
        const int k = lq + 16 * j;
        float4 av = make_float4(0.f, 0.f, 0.f, 0.f);
        if (valid) {
            if (j < 8) av = *reinterpret_cast<const float4*>(&x[(size_t)node * 128 + k]);
            else       av = *reinterpret_cast<const float4*>(&out[(size_t)node * 128 + (k - 128)]);
        }
        const int kt = k >> 5;
        const int lane = (le & 15) + (((k & 31) >> 3) << 4);
        const int off = ((kt * 4 + nt_s) << 10) + (lane << 4) + ((k & 4) << 1);
        *reinterpret_cast<uint2*>(Asw + off) = pack4(av.x, av.y, av.z, av.w);
    }
    __syncthreads();

    f32x4 acc[2][4];
#pragma unroll
    for (int dm = 0; dm < 2; ++dm)
#pragma unroll
        for (int nt = 0; nt < 4; ++nt) acc[dm][nt] = (f32x4){0.f, 0.f, 0.f, 0.f};
#pragma unroll
    for (int kt = 0; kt < 8; ++kt) {
        bf16x8 af[4];
#pragma unroll
        for (int nt = 0; nt < 4; ++nt)
            af[nt] = *reinterpret_cast<const bf16x8*>(Asw + ((kt * 4 + nt) << 10) + (l << 4));
#pragma unroll
        for (int nt = 0; nt < 4; ++nt) {
            acc[0][nt] = __builtin_amdgcn_mfma_f32_16x16x32_bf16(u1r[0][kt], af[nt], acc[0][nt], 0, 0, 0);
            acc[1][nt] = __builtin_amdgcn_mfma_f32_16x16x32_bf16(u1r[1][kt], af[nt], acc[1][nt], 0, 0, 0);
        }
    }

#pragma unroll
    for (int dm = 0; dm < 2; ++dm) {
        const float bb[4] = {c1v[dm].x, c1v[dm].y, c1v[dm].z, c1v[dm].w};
        const int lane2 = (l & 15) + ((2 * dm + (g >> 1)) << 4);
#pragma unroll
        for (int nt = 0; nt < 4; ++nt) {
            float v0 = fmaxf(acc[dm][nt][0] + bb[0], 0.f);
            float v1 = fmaxf(acc[dm][nt][1] + bb[1], 0.f);
            float v2 = fmaxf(acc[dm][nt][2] + bb[2], 0.f);
            float v3 = fmaxf(acc[dm][nt][3] + bb[3], 0.f);
            const int off = ((w * 4 + nt) << 10) + (lane2 << 4) + ((g & 1) << 3);
            *reinterpret_cast<uint2*>(Hsw + off) = pack4(v0, v1, v2, v3);
        }
    }
    __syncthreads();

    f32x4 acc2[2][4];
#pragma unroll
    for (int dm = 0; dm < 2; ++dm)
#pragma unroll
        for (int nt = 0; nt < 4; ++nt) acc2[dm][nt] = (f32x4){0.f, 0.f, 0.f, 0.f};
#pragma unroll
    for (int kt = 0; kt < 4; ++kt) {
        bf16x8 hf[4];
#pragma unroll
        for (int nt = 0; nt < 4; ++nt)
            hf[nt] = *reinterpret_cast<const bf16x8*>(Hsw + ((kt * 4 + nt) << 10) + (l << 4));
#pragma unroll
        for (int nt = 0; nt < 4; ++nt) {
            acc2[0][nt] = __builtin_amdgcn_mfma_f32_16x16x32_bf16(u2r[0][kt], hf[nt], acc2[0][nt], 0, 0, 0);
            acc2[1][nt] = __builtin_amdgcn_mfma_f32_16x16x32_bf16(u2r[1][kt], hf[nt], acc2[1][nt], 0, 0, 0);
        }
    }

#pragma unroll
    for (int dm = 0; dm < 2; ++dm) {
        const int mbase = 32 * w + 16 * dm + 4 * g;
#pragma unroll
        for (int nt = 0; nt < 4; ++nt) {
            const int n = n0 + nt * 16 + (l & 15);
            if (n < NN) {
                float4 o;
                o.x = acc2[dm][nt][0] + c2v[dm].x;
                o.y = acc2[dm][nt][1] + c2v[dm].y;
                o.z = acc2[dm][nt][2] + c2v[dm].z;
                o.w = acc2[dm][nt][3] + c2v[dm].w;
                *reinterpret_cast<float4*>(&out[(size_t)n * 128 + mbase]) = o;
            }
        }
    }
}

extern "C" void kernel_launch(void* const* d_in, const int* in_sizes, int n_in,
                              void* d_out, int out_size, void* d_ws, size_t ws_size,
                              hipStream_t stream) {
    const float* x  = (const float*)d_in[0];
    const float* pe = (const float*)d_in[1];
    const float* W1 = (const float*)d_in[2];
    const float* b1 = (const float*)d_in[3];
    const float* W2 = (const float*)d_in[4];
    const float* b2 = (const float*)d_in[5];
    const float* U1 = (const float*)d_in[6];
    const float* c1 = (const float*)d_in[7];
    const float* U2 = (const float*)d_in[8];
    const float* c2 = (const float*)d_in[9];
    const int*   ei = (const int*)d_in[10];
    float* out = (float*)d_out;

    const size_t MB = 1 << 20;
    unsigned short* wf = (unsigned short*)d_ws;
    int* counts = (int*)((char*)d_ws + 1 * MB);
    int* offs   = (int*)((char*)d_ws + 1 * MB + 256 * 1024);
    int* bsums  = (int*)((char*)d_ws + 1 * MB + 512 * 1024);
    int* boffs  = (int*)((char*)d_ws + 1 * MB + 516 * 1024);
    int* rank   = (int*)((char*)d_ws + 2 * MB);                    // 3.2 MB
    unsigned short* xb   = (unsigned short*)((char*)d_ws + 6 * MB);  // 12.8 MB
    unsigned short* msgA = (unsigned short*)((char*)d_ws + 19 * MB);
    unsigned short* msgB = (unsigned short*)((char*)d_ws + 6 * MB);

    const size_t MSG_BYTES = (size_t)NE * 128 * 2;
    const size_t REQA = 19 * MB + MSG_BYTES;
    const size_t REQB = 6 * MB + MSG_BYTES;

    if (ws_size >= REQB) {
        const bool tierA = ws_size >= REQA;
        unsigned short* msg = tierA ? msgA : msgB;

        hipMemsetAsync(counts, 0, 50176 * sizeof(int), stream);
        if (tierA) {
            prep_all<<<6338, 256, 0, stream>>>(W1, W2, U1, U2, x, ei, wf, xb, counts, rank);
        } else {
            prep_weights<<<88, 256, 0, stream>>>(W1, W2, U1, U2, wf);
            hist_kernel<<<NE / 256, 256, 0, stream>>>(ei, counts, rank);
        }
        scan1_kernel<<<196, 256, 0, stream>>>(counts, offs, bsums);
        scan2_kernel<<<1, 256, 0, stream>>>(bsums, boffs);
        if (tierA) {
            edge_kernel2<1><<<NE / 64 / 5, 512, 0, stream>>>(x, xb, pe, b1, b2, ei, rank, offs, boffs, wf, msg);
            node_fused<1><<<(NN + 63) / 64, 512, 0, stream>>>(x, xb, c1, c2, wf, offs, boffs, counts, msg, out);
        } else {
            edge_kernel2<0><<<NE / 64 / 5, 512, 0, stream>>>(x, nullptr, pe, b1, b2, ei, rank, offs, boffs, wf, msg);
            node_fused<0><<<(NN + 63) / 64, 512, 0, stream>>>(x, nullptr, c1, c2, wf, offs, boffs, counts, msg, out);
        }
    } else {
        prep_weights<<<88, 256, 0, stream>>>(W1, W2, U1, U2, wf);
        hipMemsetAsync(out, 0, (size_t)NN * 128 * sizeof(float), stream);
        edge_atomic<<<NE / 64 / 5, 256, 0, stream>>>(x, pe, b1, b2, ei, wf, out);
        node_legacy<<<(NN + 63) / 64, 256, 0, stream>>>(x, c1, c2, wf, out);
    }
}

// Round 13
// 251.332 us; speedup vs baseline: 1.1232x; 1.1232x over previous
//
#include <hip/hip_runtime.h>

#define NN 50000
#define NE 800000

typedef __attribute__((ext_vector_type(8))) short bf16x8;
typedef __attribute__((ext_vector_type(4))) float f32x4;

// swizzled slot within a 1KB subtile (64 x 16B slots); bijective, applied on
// both write and read so correctness is layout-independent.
#define SWS(s, kt) ((s) ^ (((s) >> 3) & 6) ^ ((kt) & 3))

// packed f32->bf16 (RNE) via native instruction
__device__ __forceinline__ unsigned cvtpk(float lo, float hi) {
    unsigned r;
    asm("v_cvt_pk_bf16_f32 %0, %1, %2" : "=v"(r) : "v"(lo), "v"(hi));
    return r;
}
__device__ __forceinline__ uint2 pack4(float a, float b, float c, float d) {
    return make_uint2(cvtpk(a, b), cvtpk(c, d));
}

// ---------------------------------------------------------------------------
// Fused prep: weights->bf16 fragments | x->bf16 | dst histogram (+rank).
// ---------------------------------------------------------------------------
__device__ __forceinline__ void prep_weights_body(int tid,
        const float* __restrict__ W1, const float* __restrict__ W2,
        const float* __restrict__ U1, const float* __restrict__ U2,
        unsigned short* __restrict__ ws) {
    const float* src; unsigned short* dst; int K;
    if (tid < 6144)        { src = W1; dst = ws;         K = 192; }
    else if (tid < 10240)  { tid -= 6144;  src = W2; dst = ws + 24576; K = 128; }
    else if (tid < 18432)  { tid -= 10240; src = U1; dst = ws + 40960; K = 256; }
    else if (tid < 22528)  { tid -= 18432; src = U2; dst = ws + 73728; K = 128; }
    else return;
    const int m = tid & 127, k = (tid >> 7) * 4;
    const int KT = K >> 5;
    uint2 p = pack4(src[(k + 0) * 128 + m], src[(k + 1) * 128 + m],
                    src[(k + 2) * 128 + m], src[(k + 3) * 128 + m]);
    const int mt = m >> 4, kt = k >> 5, lane = (m & 15) + (((k & 31) >> 3) << 4);
    const int off = (((mt * KT + kt) << 9) + (lane << 3) + ((k & 4) ? 4 : 0));
    *reinterpret_cast<uint2*>(dst + off) = p;
}

__global__ __launch_bounds__(256)
void prep_all(const float* __restrict__ W1, const float* __restrict__ W2,
              const float* __restrict__ U1, const float* __restrict__ U2,
              const float* __restrict__ x, const int* __restrict__ ei,
              unsigned short* __restrict__ ws, unsigned short* __restrict__ xb,
              int* __restrict__ counts, int* __restrict__ rank) {
    const int b = blockIdx.x;
    if (b < 88) {
        prep_weights_body(b * 256 + threadIdx.x, W1, W2, U1, U2, ws);
    } else if (b < 3213) {
        const int i = ((b - 88) * 256 + threadIdx.x) * 8;
        if (i >= NN * 128) return;
        const float4 a = *reinterpret_cast<const float4*>(&x[i]);
        const float4 c = *reinterpret_cast<const float4*>(&x[i + 4]);
        *reinterpret_cast<uint4*>(&xb[i]) =
            make_uint4(cvtpk(a.x, a.y), cvtpk(a.z, a.w), cvtpk(c.x, c.y), cvtpk(c.z, c.w));
    } else {
        const int e = (b - 3213) * 256 + threadIdx.x;
        if (e < NE) rank[e] = atomicAdd(&counts[ei[NE + e]], 1);
    }
}

__global__ void prep_weights(const float* __restrict__ W1, const float* __restrict__ W2,
                             const float* __restrict__ U1, const float* __restrict__ U2,
                             unsigned short* __restrict__ ws) {
    prep_weights_body(blockIdx.x * blockDim.x + threadIdx.x, W1, W2, U1, U2, ws);
}

__global__ void hist_kernel(const int* __restrict__ ei, int* __restrict__ counts,
                            int* __restrict__ rank) {
    const int e = blockIdx.x * blockDim.x + threadIdx.x;
    if (e < NE) rank[e] = atomicAdd(&counts[ei[NE + e]], 1);
}

// ---------------------------------------------------------------------------
// CSR build: 3-kernel parallel scan -> csrfin (no atomics)
// ---------------------------------------------------------------------------
__global__ __launch_bounds__(256)
void scan1_kernel(const int* __restrict__ counts, int* __restrict__ offs,
                  int* __restrict__ bsums) {
    __shared__ int wsum[4];
    const int t = threadIdx.x, lane = t & 63, w = t >> 6;
    const int i = blockIdx.x * 256 + t;
    const int v = (i < NN) ? counts[i] : 0;
    int s = v;
#pragma unroll
    for (int d = 1; d < 64; d <<= 1) {
        int u = __shfl_up(s, d, 64);
        if (lane >= d) s += u;
    }
    if (lane == 63) wsum[w] = s;
    __syncthreads();
    if (t == 0) {
        int a = 0;
#pragma unroll
        for (int k = 0; k < 4; ++k) { int tmp = wsum[k]; wsum[k] = a; a += tmp; }
    }
    __syncthreads();
    const int excl = wsum[w] + s - v;
    if (i < NN) offs[i] = excl;
    if (t == 255) bsums[blockIdx.x] = wsum[3] + s;
}

__global__ __launch_bounds__(256)
void scan2_kernel(const int* __restrict__ bsums, int* __restrict__ boffs) {
    __shared__ int wsum[4];
    const int t = threadIdx.x, lane = t & 63, w = t >> 6;
    const int v = (t < 196) ? bsums[t] : 0;
    int s = v;
#pragma unroll
    for (int d = 1; d < 64; d <<= 1) {
        int u = __shfl_up(s, d, 64);
        if (lane >= d) s += u;
    }
    if (lane == 63) wsum[w] = s;
    __syncthreads();
    if (t == 0) {
        int a = 0;
#pragma unroll
        for (int k = 0; k < 4; ++k) { int tmp = wsum[k]; wsum[k] = a; a += tmp; }
    }
    __syncthreads();
    boffs[t] = wsum[w] + s - v;
}

__global__ __launch_bounds__(256)
void scan3_kernel(int* __restrict__ offs, const int* __restrict__ boffs) {
    const int i = blockIdx.x * 256 + threadIdx.x;
    if (i < NN) offs[i] += boffs[i >> 8];
}

// csrpos[e] = offs[dst] + rank[e]  (atomic-free)
__global__ void csrfin_kernel(const int* __restrict__ ei, const int* __restrict__ offs,
                              const int* __restrict__ rank, int* __restrict__ csrpos) {
    const int e = blockIdx.x * blockDim.x + threadIdx.x;
    if (e < NE) csrpos[e] = offs[ei[NE + e]] + rank[e];
}

// ---------------------------------------------------------------------------
// Edge kernel (r11-proven, 2 barriers/tile): 512 thr = 8 waves, 1 mtile/wave.
// sync-A removed: stage(ti) vs L1-reads(ti-1) is ordered by sync-C(ti-1)
// (s_barrier drains lgkmcnt); Hwrite(ti) vs L2-reads(ti-1) by sync-B(ti).
// ---------------------------------------------------------------------------
template <int XBF>
__global__ __launch_bounds__(512)
void edge_kernel2(const float* __restrict__ x,
                  const unsigned short* __restrict__ xb,
                  const float* __restrict__ pe,
                  const float* __restrict__ b1,
                  const float* __restrict__ b2,
                  const int* __restrict__ ei,
                  const int* __restrict__ csrpos,
                  const unsigned short* __restrict__ wf,
                  unsigned short* __restrict__ msg)
{
    __shared__ __align__(16) unsigned char Asw[24576];  // 6 kt x 4 nt x 1KB
    __shared__ __align__(16) unsigned char Hsw[16384];  // 4 kt x 4 nt x 1KB

    const int t = threadIdx.x;
    const int l = t & 63;
    const int w = t >> 6;       // wave = mtile
    const int g = l >> 4;

    bf16x8 w1r[6], w2r[4];
    {
        const bf16x8* wp1 = reinterpret_cast<const bf16x8*>(wf);
        const bf16x8* wp2 = reinterpret_cast<const bf16x8*>(wf + 24576);
#pragma unroll
        for (int kt = 0; kt < 6; ++kt) w1r[kt] = wp1[(w * 6 + kt) * 64 + l];
#pragma unroll
        for (int kt = 0; kt < 4; ++kt) w2r[kt] = wp2[(w * 4 + kt) * 64 + l];
    }
    const float4 b1v = *reinterpret_cast<const float4*>(&b1[16 * w + 4 * g]);
    const float4 b2v = *reinterpret_cast<const float4*>(&b2[16 * w + 4 * g]);

    const int le = t >> 3;              // staged edge 0..63
    const int sub = t & 7;              // k-subgroup
    const int nt_s = le >> 4;
    const int lane_s = (le & 15) + ((sub & 3) << 4);

    uint4  rxb[2];
    float4 rxf[4];
    float4 rpf[2];

    const int tile0 = blockIdx.x * 5;

    // prefetch tile 0
    {
        const int e0 = tile0 * 64;
        const int src = ei[e0 + le];
        if constexpr (XBF) {
#pragma unroll
            for (int j = 0; j < 2; ++j)
                rxb[j] = *reinterpret_cast<const uint4*>(&xb[(size_t)src * 128 + sub * 8 + 64 * j]);
        } else {
#pragma unroll
            for (int j = 0; j < 2; ++j) {
                rxf[2 * j]     = *reinterpret_cast<const float4*>(&x[(size_t)src * 128 + sub * 8 + 64 * j]);
                rxf[2 * j + 1] = *reinterpret_cast<const float4*>(&x[(size_t)src * 128 + sub * 8 + 64 * j + 4]);
            }
        }
        rpf[0] = *reinterpret_cast<const float4*>(&pe[(size_t)(e0 + le) * 64 + sub * 8]);
        rpf[1] = *reinterpret_cast<const float4*>(&pe[(size_t)(e0 + le) * 64 + sub * 8 + 4]);
    }

    for (int ti = 0; ti < 5; ++ti) {
        const int e0 = (tile0 + ti) * 64;
        int cp[4];
#pragma unroll
        for (int nt = 0; nt < 4; ++nt) cp[nt] = csrpos[e0 + nt * 16 + (l & 15)];

        // (sync-A removed: ordered by previous iteration's sync-C)

        // ---- stage regs -> Asw (swizzled B-fragment layout) ----
        {
#pragma unroll
            for (int j = 0; j < 2; ++j) {
                const int kt = (sub >> 2) + 2 * j;
                uint4 v;
                if constexpr (XBF) v = rxb[j];
                else v = make_uint4(cvtpk(rxf[2 * j].x, rxf[2 * j].y), cvtpk(rxf[2 * j].z, rxf[2 * j].w),
                                    cvtpk(rxf[2 * j + 1].x, rxf[2 * j + 1].y), cvtpk(rxf[2 * j + 1].z, rxf[2 * j + 1].w));
                *reinterpret_cast<uint4*>(Asw + ((kt * 4 + nt_s) << 10) + (SWS(lane_s, kt) << 4)) = v;
            }
            const int ktp = 4 + (sub >> 2);
            *reinterpret_cast<uint4*>(Asw + ((ktp * 4 + nt_s) << 10) + (SWS(lane_s, ktp) << 4)) =
                make_uint4(cvtpk(rpf[0].x, rpf[0].y), cvtpk(rpf[0].z, rpf[0].w),
                           cvtpk(rpf[1].x, rpf[1].y), cvtpk(rpf[1].z, rpf[1].w));
        }

        // prefetch next tile (loads overlap this tile's MFMAs)
        if (ti < 4) {
            const int e0n = e0 + 64;
            const int srcn = ei[e0n + le];
            if constexpr (XBF) {
#pragma unroll
                for (int j = 0; j < 2; ++j)
                    rxb[j] = *reinterpret_cast<const uint4*>(&xb[(size_t)srcn * 128 + sub * 8 + 64 * j]);
            } else {
#pragma unroll
                for (int j = 0; j < 2; ++j) {
                    rxf[2 * j]     = *reinterpret_cast<const float4*>(&x[(size_t)srcn * 128 + sub * 8 + 64 * j]);
                    rxf[2 * j + 1] = *reinterpret_cast<const float4*>(&x[(size_t)srcn * 128 + sub * 8 + 64 * j + 4]);
                }
            }
            rpf[0] = *reinterpret_cast<const float4*>(&pe[(size_t)(e0n + le) * 64 + sub * 8]);
            rpf[1] = *reinterpret_cast<const float4*>(&pe[(size_t)(e0n + le) * 64 + sub * 8 + 4]);
        }

        __syncthreads();   // [B] Asw staged

        // ---- layer 1: K=192 ----
        f32x4 acc[4];
#pragma unroll
        for (int nt = 0; nt < 4; ++nt) acc[nt] = (f32x4){0.f, 0.f, 0.f, 0.f};
#pragma unroll
        for (int kt = 0; kt < 6; ++kt) {
#pragma unroll
            for (int nt = 0; nt < 4; ++nt) {
                const bf16x8 af = *reinterpret_cast<const bf16x8*>(
                    Asw + ((kt * 4 + nt) << 10) + (SWS(l, kt) << 4));
                acc[nt] = __builtin_amdgcn_mfma_f32_16x16x32_bf16(w1r[kt], af, acc[nt], 0, 0, 0);
            }
        }

        // ---- bias + relu -> Hsw ----
        {
            const int kt2 = (16 * w + 4 * g) >> 5;
            const int lane2 = (l & 15) + ((2 * (w & 1) + (g >> 1)) << 4);
            const int bo = (g & 1) << 3;
#pragma unroll
            for (int nt = 0; nt < 4; ++nt) {
                float v0 = fmaxf(acc[nt][0] + b1v.x, 0.f);
                float v1 = fmaxf(acc[nt][1] + b1v.y, 0.f);
                float v2 = fmaxf(acc[nt][2] + b1v.z, 0.f);
                float v3 = fmaxf(acc[nt][3] + b1v.w, 0.f);
                *reinterpret_cast<uint2*>(Hsw + ((kt2 * 4 + nt) << 10) + (SWS(lane2, kt2) << 4) + bo) =
                    make_uint2(cvtpk(v0, v1), cvtpk(v2, v3));
            }
        }

        __syncthreads();   // [C] Hsw ready; all Asw L1 reads complete

        // ---- layer 2: K=128 ----
#pragma unroll
        for (int nt = 0; nt < 4; ++nt) acc[nt] = (f32x4){0.f, 0.f, 0.f, 0.f};
#pragma unroll
        for (int kt = 0; kt < 4; ++kt) {
#pragma unroll
            for (int nt = 0; nt < 4; ++nt) {
                const bf16x8 hf = *reinterpret_cast<const bf16x8*>(
                    Hsw + ((kt * 4 + nt) << 10) + (SWS(l, kt) << 4));
                acc[nt] = __builtin_amdgcn_mfma_f32_16x16x32_bf16(w2r[kt], hf, acc[nt], 0, 0, 0);
            }
        }

        // ---- bias + CSR-ordered msg store ----
        const int mbase = 16 * w + 4 * g;
#pragma unroll
        for (int nt = 0; nt < 4; ++nt) {
            *reinterpret_cast<uint2*>(&msg[(size_t)cp[nt] * 128 + mbase]) =
                make_uint2(cvtpk(acc[nt][0] + b2v.x, acc[nt][1] + b2v.y),
                           cvtpk(acc[nt][2] + b2v.z, acc[nt][3] + b2v.w));
        }
    }
}

// ---------------------------------------------------------------------------
// Fused node kernel (r9-proven, unchanged)
// ---------------------------------------------------------------------------
template <int XBF>
__global__ __launch_bounds__(512)
void node_fused(const float* __restrict__ x,
                const unsigned short* __restrict__ xb,
                const float* __restrict__ c1,
                const float* __restrict__ c2,
                const unsigned short* __restrict__ wf,
                const int* __restrict__ offs,
                const int* __restrict__ counts,
                const unsigned short* __restrict__ msg,
                float* __restrict__ out)
{
    __shared__ __align__(16) unsigned char Asw[32768];
    __shared__ __align__(16) unsigned char Hsw[16384];

    const int t = threadIdx.x;
    const int l = t & 63;
    const int w = t >> 6;
    const int g = l >> 4;

    bf16x8 u1r[8], u2r[4];
    {
        const bf16x8* up1 = reinterpret_cast<const bf16x8*>(wf + 40960);
        const bf16x8* up2 = reinterpret_cast<const bf16x8*>(wf + 73728);
#pragma unroll
        for (int kt = 0; kt < 8; ++kt) u1r[kt] = up1[(w * 8 + kt) * 64 + l];
#pragma unroll
        for (int kt = 0; kt < 4; ++kt) u2r[kt] = up2[(w * 4 + kt) * 64 + l];
    }
    const float4 c1v = *reinterpret_cast<const float4*>(&c1[16 * w + 4 * g]);
    const float4 c2v = *reinterpret_cast<const float4*>(&c2[16 * w + 4 * g]);

    const int n0 = blockIdx.x * 64;
    const int le = t >> 3;
    const int q  = t & 7;
    const int nt_s = le >> 4;
    const int node = n0 + le;
    const bool valid = node < NN;

    float a16[16];
#pragma unroll
    for (int i = 0; i < 16; ++i) a16[i] = 0.f;
    int start = 0, cnt = 0;
    if (valid) { start = offs[node]; cnt = counts[node]; }
    for (int j = 0; j < cnt; ++j) {
        const uint4* mp = reinterpret_cast<const uint4*>(&msg[(size_t)(start + j) * 128 + q * 16]);
        const uint4 u0 = mp[0], u1 = mp[1];
        const unsigned arr[8] = {u0.x, u0.y, u0.z, u0.w, u1.x, u1.y, u1.z, u1.w};
#pragma unroll
        for (int r = 0; r < 8; ++r) {
            union { unsigned u; float f; } lo, hi;
            lo.u = arr[r] << 16;
            hi.u = arr[r] & 0xFFFF0000u;
            a16[2 * r]     += lo.f;
            a16[2 * r + 1] += hi.f;
        }
    }

#pragma unroll
    for (int i = 0; i < 2; ++i) {
        const int o = 2 * q + i;
        const int kt = o >> 2;
        const int slot = (le & 15) + ((o & 3) << 4);
        uint4 v = make_uint4(0u, 0u, 0u, 0u);
        if (valid) {
            if constexpr (XBF) {
                v = *reinterpret_cast<const uint4*>(&xb[(size_t)node * 128 + o * 8]);
            } else {
                const float4 f0 = *reinterpret_cast<const float4*>(&x[(size_t)node * 128 + o * 8]);
                const float4 f1 = *reinterpret_cast<const float4*>(&x[(size_t)node * 128 + o * 8 + 4]);
                v = make_uint4(cvtpk(f0.x, f0.y), cvtpk(f0.z, f0.w),
                               cvtpk(f1.x, f1.y), cvtpk(f1.z, f1.w));
            }
        }
        *reinterpret_cast<uint4*>(Asw + ((kt * 4 + nt_s) << 10) + (SWS(slot, kt) << 4)) = v;
    }

    {
        const int kt = 4 + (q >> 1);
#pragma unroll
        for (int i = 0; i < 2; ++i) {
            const int j4 = 2 * (q & 1) + i;
            const int slot = (le & 15) + (j4 << 4);
            *reinterpret_cast<uint4*>(Asw + ((kt * 4 + nt_s) << 10) + (SWS(slot, kt) << 4)) =
                make_uint4(cvtpk(a16[8 * i + 0], a16[8 * i + 1]), cvtpk(a16[8 * i + 2], a16[8 * i + 3]),
                           cvtpk(a16[8 * i + 4], a16[8 * i + 5]), cvtpk(a16[8 * i + 6], a16[8 * i + 7]));
        }
    }
    __syncthreads();

    f32x4 acc[4];
#pragma unroll
    for (int nt = 0; nt < 4; ++nt) acc[nt] = (f32x4){0.f, 0.f, 0.f, 0.f};
#pragma unroll
    for (int kt = 0; kt < 8; ++kt) {
#pragma unroll
        for (int nt = 0; nt < 4; ++nt) {
            const bf16x8 af = *reinterpret_cast<const bf16x8*>(
                Asw + ((kt * 4 + nt) << 10) + (SWS(l, kt) << 4));
            acc[nt] = __builtin_amdgcn_mfma_f32_16x16x32_bf16(u1r[kt], af, acc[nt], 0, 0, 0);
        }
    }

    {
        const int kt2 = (16 * w + 4 * g) >> 5;
        const int lane2 = (l & 15) + ((2 * (w & 1) + (g >> 1)) << 4);
        const int bo = (g & 1) << 3;
#pragma unroll
        for (int nt = 0; nt < 4; ++nt) {
            float v0 = fmaxf(acc[nt][0] + c1v.x, 0.f);
            float v1 = fmaxf(acc[nt][1] + c1v.y, 0.f);
            float v2 = fmaxf(acc[nt][2] + c1v.z, 0.f);
            float v3 = fmaxf(acc[nt][3] + c1v.w, 0.f);
            *reinterpret_cast<uint2*>(Hsw + ((kt2 * 4 + nt) << 10) + (SWS(lane2, kt2) << 4) + bo) =
                make_uint2(cvtpk(v0, v1), cvtpk(v2, v3));
        }
    }
    __syncthreads();

    f32x4 a2[4];
#pragma unroll
    for (int nt = 0; nt < 4; ++nt) a2[nt] = (f32x4){0.f, 0.f, 0.f, 0.f};
#pragma unroll
    for (int kt = 0; kt < 4; ++kt) {
#pragma unroll
        for (int nt = 0; nt < 4; ++nt) {
            const bf16x8 hf = *reinterpret_cast<const bf16x8*>(
                Hsw + ((kt * 4 + nt) << 10) + (SWS(l, kt) << 4));
            a2[nt] = __builtin_amdgcn_mfma_f32_16x16x32_bf16(u2r[kt], hf, a2[nt], 0, 0, 0);
        }
    }

    const int mbase = 16 * w + 4 * g;
#pragma unroll
    for (int nt = 0; nt < 4; ++nt) {
        const int n = n0 + nt * 16 + (l & 15);
        if (n < NN) {
            float4 o;
            o.x = a2[nt][0] + c2v.x;
            o.y = a2[nt][1] + c2v.y;
            o.z = a2[nt][2] + c2v.z;
            o.w = a2[nt][3] + c2v.w;
            *reinterpret_cast<float4*>(&out[(size_t)n * 128 + mbase]) = o;
        }
    }
}

// ---------------------------------------------------------------------------
// Legacy fallback (small workspace): atomic scatter edge + in-place node.
// ---------------------------------------------------------------------------
__global__ __launch_bounds__(256)
void edge_atomic(const float* __restrict__ x, const float* __restrict__ pe,
                 const float* __restrict__ b1, const float* __restrict__ b2,
                 const int* __restrict__ ei, const unsigned short* __restrict__ wf,
                 float* __restrict__ agg)
{
    __shared__ __align__(16) unsigned char smem[24576 + 16384];
    unsigned char* Asw = smem;
    unsigned char* Hsw = smem + 24576;

    const int t = threadIdx.x;
    const int l = t & 63;
    const int w = t >> 6;
    const int g = l >> 4;

    bf16x8 w1r[2][6], w2r[2][4];
    {
        const bf16x8* wp1 = reinterpret_cast<const bf16x8*>(wf);
        const bf16x8* wp2 = reinterpret_cast<const bf16x8*>(wf + 24576);
#pragma unroll
        for (int dm = 0; dm < 2; ++dm) {
            const int mt = 2 * w + dm;
#pragma unroll
            for (int kt = 0; kt < 6; ++kt) w1r[dm][kt] = wp1[(mt * 6 + kt) * 64 + l];
#pragma unroll
            for (int kt = 0; kt < 4; ++kt) w2r[dm][kt] = wp2[(mt * 4 + kt) * 64 + l];
        }
    }
    float4 b1v[2], b2v[2];
#pragma unroll
    for (int dm = 0; dm < 2; ++dm) {
        b1v[dm] = *reinterpret_cast<const float4*>(&b1[32 * w + 16 * dm + 4 * g]);
        b2v[dm] = *reinterpret_cast<const float4*>(&b2[32 * w + 16 * dm + 4 * g]);
    }

    const int le = t >> 2;
    const int lq = (t & 3) * 4;
    const int nt_s = le >> 4;

    for (int tile = blockIdx.x * 5; tile < blockIdx.x * 5 + 5; ++tile) {
        const int e0 = tile * 64;
        const int src = ei[e0 + le];
#pragma unroll
        for (int j = 0; j < 12; ++j) {
            const int k = lq + 16 * j;
            float4 av;
            if (j < 8) av = *reinterpret_cast<const float4*>(&x[(size_t)src * 128 + k]);
            else       av = *reinterpret_cast<const float4*>(&pe[(size_t)(e0 + le) * 64 + (k - 128)]);
            const int kt = k >> 5;
            const int lane = (le & 15) + (((k & 31) >> 3) << 4);
            const int off = ((kt * 4 + nt_s) << 10) + (lane << 4) + ((k & 4) << 1);
            *reinterpret_cast<uint2*>(Asw + off) = pack4(av.x, av.y, av.z, av.w);
        }
        int dstv[4];
#pragma unroll
        for (int nt = 0; nt < 4; ++nt) dstv[nt] = ei[NE + e0 + nt * 16 + (l & 15)];
        __syncthreads();

        f32x4 acc[2][4];
#pragma unroll
        for (int dm = 0; dm < 2; ++dm)
#pragma unroll
            for (int nt = 0; nt < 4; ++nt) acc[dm][nt] = (f32x4){0.f, 0.f, 0.f, 0.f};
#pragma unroll
        for (int kt = 0; kt < 6; ++kt) {
#pragma unroll
            for (int nt = 0; nt < 4; ++nt) {
                const bf16x8 af = *reinterpret_cast<const bf16x8*>(Asw + ((kt * 4 + nt) << 10) + (l << 4));
                acc[0][nt] = __builtin_amdgcn_mfma_f32_16x16x32_bf16(w1r[0][kt], af, acc[0][nt], 0, 0, 0);
                acc[1][nt] = __builtin_amdgcn_mfma_f32_16x16x32_bf16(w1r[1][kt], af, acc[1][nt], 0, 0, 0);
            }
        }
#pragma unroll
        for (int dm = 0; dm < 2; ++dm) {
            const float bb[4] = {b1v[dm].x, b1v[dm].y, b1v[dm].z, b1v[dm].w};
            const int lane2 = (l & 15) + ((2 * dm + (g >> 1)) << 4);
#pragma unroll
            for (int nt = 0; nt < 4; ++nt) {
                float v0 = fmaxf(acc[dm][nt][0] + bb[0], 0.f);
                float v1 = fmaxf(acc[dm][nt][1] + bb[1], 0.f);
                float v2 = fmaxf(acc[dm][nt][2] + bb[2], 0.f);
                float v3 = fmaxf(acc[dm][nt][3] + bb[3], 0.f);
                const int off = ((w * 4 + nt) << 10) + (lane2 << 4) + ((g & 1) << 3);
                *reinterpret_cast<uint2*>(Hsw + off) = pack4(v0, v1, v2, v3);
            }
        }
        __syncthreads();

        f32x4 acc2[2][4];
#pragma unroll
        for (int dm = 0; dm < 2; ++dm)
#pragma unroll
            for (int nt = 0; nt < 4; ++nt) acc2[dm][nt] = (f32x4){0.f, 0.f, 0.f, 0.f};
#pragma unroll
        for (int kt = 0; kt < 4; ++kt) {
#pragma unroll
            for (int nt = 0; nt < 4; ++nt) {
                const bf16x8 hf = *reinterpret_cast<const bf16x8*>(Hsw + ((kt * 4 + nt) << 10) + (l << 4));
                acc2[0][nt] = __builtin_amdgcn_mfma_f32_16x16x32_bf16(w2r[0][kt], hf, acc2[0][nt], 0, 0, 0);
                acc2[1][nt] = __builtin_amdgcn_mfma_f32_16x16x32_bf16(w2r[1][kt], hf, acc2[1][nt], 0, 0, 0);
            }
        }
#pragma unroll
        for (int dm = 0; dm < 2; ++dm) {
            const float bb[4] = {b2v[dm].x, b2v[dm].y, b2v[dm].z, b2v[dm].w};
            const int mbase = 32 * w + 16 * dm + 4 * g;
#pragma unroll
            for (int nt = 0; nt < 4; ++nt) {
                float* ap = &agg[(size_t)dstv[nt] * 128 + mbase];
                atomicAdd(ap + 0, acc2[dm][nt][0] + bb[0]);
                atomicAdd(ap + 1, acc2[dm][nt][1] + bb[1]);
                atomicAdd(ap + 2, acc2[dm][nt][2] + bb[2]);
                atomicAdd(ap + 3, acc2[dm][nt][3] + bb[3]);
            }
        }
    }
}

__global__ __launch_bounds__(256)
void node_legacy(const float* __restrict__ x,
                 const float* __restrict__ c1,
                 const float* __restrict__ c2,
                 const unsigned short* __restrict__ wf,
                 float* __restrict__ out)
{
    __shared__ __align__(16) unsigned char smem[32768 + 16384];
    unsigned char* Asw = smem;
    unsigned char* Hsw = smem + 32768;

    const int t = threadIdx.x;
    const int l = t & 63;
    const int w = t >> 6;
    const int g = l >> 4;

    bf16x8 u1r[2][8], u2r[2][4];
    {
        const bf16x8* up1 = reinterpret_cast<const bf16x8*>(wf + 40960);
        const bf16x8* up2 = reinterpret_cast<const bf16x8*>(wf + 73728);
#pragma unroll
        for (int dm = 0; dm < 2; ++dm) {
            const int mt = 2 * w + dm;
#pragma unroll
            for (int kt = 0; kt < 8; ++kt) u1r[dm][kt] = up1[(mt * 8 + kt) * 64 + l];
#pragma unroll
            for (int kt = 0; kt < 4; ++kt) u2r[dm][kt] = up2[(mt * 4 + kt) * 64 + l];
        }
    }
    float4 c1v[2], c2v[2];
#pragma unroll
    for (int dm = 0; dm < 2; ++dm) {
        c1v[dm] = *reinterpret_cast<const float4*>(&c1[32 * w + 16 * dm + 4 * g]);
        c2v[dm] = *reinterpret_cast<const float4*>(&c2[32 * w + 16 * dm + 4 * g]);
    }

    const int n0 = blockIdx.x * 64;
    const int le = t >> 2;
    const int lq = (t & 3) * 4;
    const int nt_s = le >> 4;
    const int node = n0 + le;
    const bool valid = node < NN;

#pragma unroll
    for (int j = 0; j < 16; ++j) {
        const int k = lq + 16 * j;
        float4 av = make_float4(0.f, 0.f, 0.f, 0.f);
        if (valid) {
            if (j < 8) av = *reinterpret_cast<const float4*>(&x[(size_t)node * 128 + k]);
            else       av = *reinterpret_cast<const float4*>(&out[(size_t)node * 128 + (k - 128)]);
        }
        const int kt = k >> 5;
        const int lane = (le & 15) + (((k & 31) >> 3) << 4);
        const int off = ((kt * 4 + nt_s) << 10) + (lane << 4) + ((k & 4) << 1);
        *reinterpret_cast<uint2*>(Asw + off) = pack4(av.x, av.y, av.z, av.w);
    }
    __syncthreads();

    f32x4 acc[2][4];
#pragma unroll
    for (int dm = 0; dm < 2; ++dm)
#pragma unroll
        for (int nt = 0; nt < 4; ++nt) acc[dm][nt] = (f32x4){0.f, 0.f, 0.f, 0.f};
#pragma unroll
    for (int kt = 0; kt < 8; ++kt) {
        bf16x8 af[4];
#pragma unroll
        for (int nt = 0; nt < 4; ++nt)
            af[nt] = *reinterpret_cast<const bf16x8*>(Asw + ((kt * 4 + nt) << 10) + (l << 4));
#pragma unroll
        for (int nt = 0; nt < 4; ++nt) {
            acc[0][nt] = __builtin_amdgcn_mfma_f32_16x16x32_bf16(u1r[0][kt], af[nt], acc[0][nt], 0, 0, 0);
            acc[1][nt] = __builtin_amdgcn_mfma_f32_16x16x32_bf16(u1r[1][kt], af[nt], acc[1][nt], 0, 0, 0);
        }
    }

#pragma unroll
    for (int dm = 0; dm < 2; ++dm) {
        const float bb[4] = {c1v[dm].x, c1v[dm].y, c1v[dm].z, c1v[dm].w};
        const int lane2 = (l & 15) + ((2 * dm + (g >> 1)) << 4);
#pragma unroll
        for (int nt = 0; nt < 4; ++nt) {
            float v0 = fmaxf(acc[dm][nt][0] + bb[0], 0.f);
            float v1 = fmaxf(acc[dm][nt][1] + bb[1], 0.f);
            float v2 = fmaxf(acc[dm][nt][2] + bb[2], 0.f);
            float v3 = fmaxf(acc[dm][nt][3] + bb[3], 0.f);
            const int off = ((w * 4 + nt) << 10) + (lane2 << 4) + ((g & 1) << 3);
            *reinterpret_cast<uint2*>(Hsw + off) = pack4(v0, v1, v2, v3);
        }
    }
    __syncthreads();

    f32x4 acc2[2][4];
#pragma unroll
    for (int dm = 0; dm < 2; ++dm)
#pragma unroll
        for (int nt = 0; nt < 4; ++nt) acc2[dm][nt] = (f32x4){0.f, 0.f, 0.f, 0.f};
#pragma unroll
    for (int kt = 0; kt < 4; ++kt) {
        bf16x8 hf[4];
#pragma unroll
        for (int nt = 0; nt < 4; ++nt)
            hf[nt] = *reinterpret_cast<const bf16x8*>(Hsw + ((kt * 4 + nt) << 10) + (l << 4));
#pragma unroll
        for (int nt = 0; nt < 4; ++nt) {
            acc2[0][nt] = __builtin_amdgcn_mfma_f32_16x16x32_bf16(u2r[0][kt], hf[nt], acc2[0][nt], 0, 0, 0);
            acc2[1][nt] = __builtin_amdgcn_mfma_f32_16x16x32_bf16(u2r[1][kt], hf[nt], acc2[1][nt], 0, 0, 0);
        }
    }

#pragma unroll
    for (int dm = 0; dm < 2; ++dm) {
        const int mbase = 32 * w + 16 * dm + 4 * g;
#pragma unroll
        for (int nt = 0; nt < 4; ++nt) {
            const int n = n0 + nt * 16 + (l & 15);
            if (n < NN) {
                float4 o;
                o.x = acc2[dm][nt][0] + c2v[dm].x;
                o.y = acc2[dm][nt][1] + c2v[dm].y;
                o.z = acc2[dm][nt][2] + c2v[dm].z;
                o.w = acc2[dm][nt][3] + c2v[dm].w;
                *reinterpret_cast<float4*>(&out[(size_t)n * 128 + mbase]) = o;
            }
        }
    }
}

extern "C" void kernel_launch(void* const* d_in, const int* in_sizes, int n_in,
                              void* d_out, int out_size, void* d_ws, size_t ws_size,
                              hipStream_t stream) {
    const float* x  = (const float*)d_in[0];
    const float* pe = (const float*)d_in[1];
    const float* W1 = (const float*)d_in[2];
    const float* b1 = (const float*)d_in[3];
    const float* W2 = (const float*)d_in[4];
    const float* b2 = (const float*)d_in[5];
    const float* U1 = (const float*)d_in[6];
    const float* c1 = (const float*)d_in[7];
    const float* U2 = (const float*)d_in[8];
    const float* c2 = (const float*)d_in[9];
    const int*   ei = (const int*)d_in[10];
    float* out = (float*)d_out;

    const size_t MB = 1 << 20;
    unsigned short* wf = (unsigned short*)d_ws;
    int* counts = (int*)((char*)d_ws + 1 * MB);
    int* offs   = (int*)((char*)d_ws + 1 * MB + 256 * 1024);
    int* bsums  = (int*)((char*)d_ws + 1 * MB + 512 * 1024);
    int* boffs  = (int*)((char*)d_ws + 1 * MB + 516 * 1024);
    int* csrpos = (int*)((char*)d_ws + 2 * MB);                    // 3.2 MB
    int* rank   = (int*)((char*)d_ws + 6 * MB);                    // 3.2 MB
    unsigned short* xb   = (unsigned short*)((char*)d_ws + 10 * MB);  // 12.8 MB
    unsigned short* msgA = (unsigned short*)((char*)d_ws + 23 * MB);
    unsigned short* msgB = (unsigned short*)((char*)d_ws + 10 * MB);

    const size_t MSG_BYTES = (size_t)NE * 128 * 2;
    const size_t REQA = 23 * MB + MSG_BYTES;
    const size_t REQB = 10 * MB + MSG_BYTES;

    if (ws_size >= REQB) {
        const bool tierA = ws_size >= REQA;
        unsigned short* msg = tierA ? msgA : msgB;

        hipMemsetAsync(counts, 0, 50176 * sizeof(int), stream);
        if (tierA) {
            prep_all<<<6338, 256, 0, stream>>>(W1, W2, U1, U2, x, ei, wf, xb, counts, rank);
        } else {
            prep_weights<<<88, 256, 0, stream>>>(W1, W2, U1, U2, wf);
            hist_kernel<<<NE / 256, 256, 0, stream>>>(ei, counts, rank);
        }
        scan1_kernel<<<196, 256, 0, stream>>>(counts, offs, bsums);
        scan2_kernel<<<1, 256, 0, stream>>>(bsums, boffs);
        scan3_kernel<<<196, 256, 0, stream>>>(offs, boffs);
        csrfin_kernel<<<NE / 256, 256, 0, stream>>>(ei, offs, rank, csrpos);
        if (tierA) {
            edge_kernel2<1><<<NE / 64 / 5, 512, 0, stream>>>(x, xb, pe, b1, b2, ei, csrpos, wf, msg);
            node_fused<1><<<(NN + 63) / 64, 512, 0, stream>>>(x, xb, c1, c2, wf, offs, counts, msg, out);
        } else {
            edge_kernel2<0><<<NE / 64 / 5, 512, 0, stream>>>(x, nullptr, pe, b1, b2, ei, csrpos, wf, msg);
            node_fused<0><<<(NN + 63) / 64, 512, 0, stream>>>(x, nullptr, c1, c2, wf, offs, counts, msg, out);
        }
    } else {
        prep_weights<<<88, 256, 0, stream>>>(W1, W2, U1, U2, wf);
        hipMemsetAsync(out, 0, (size_t)NN * 128 * sizeof(float), stream);
        edge_atomic<<<NE / 64 / 5, 256, 0, stream>>>(x, pe, b1, b2, ei, wf, out);
        node_legacy<<<(NN + 63) / 64, 256, 0, stream>>>(x, c1, c2, wf, out);
    }
}